// Round 2
// baseline (1320.243 us; speedup 1.0000x reference)
//
#include <hip/hip_runtime.h>
#include <math.h>

// Problem constants
#define B_   8
#define CI_  64
#define CO_  64
#define H_   256
#define W_   256
#define WC_  64    // cols kept (w < 64); everything beyond is zero in out_ft
#define HR_  128   // rows kept: hr<64 -> row hr ; hr>=64 -> row hr+128 (192..255)
#define NE_  15
#define RK_  4
#define NB_  4     // batches per stage-A/B chunk (2 chunks total)

#define TWOPI_256 0.024543692606170259f  // 2*pi/256

// ---------------------------------------------------------------------------
// Stage A (per chunk of NB_ batches): Xc[row,w] = sum_q x[row,q]*cis(-2pi q w/256)
// row = chunk-local (b*CI+i)*H + p ; block = 4 rows, 64 threads per row
// ---------------------------------------------------------------------------
__global__ __launch_bounds__(256) void kA2(const float* __restrict__ x,
                                           float2* __restrict__ Xc) {
  int wid = threadIdx.x >> 6;
  int w   = threadIdx.x & 63;
  size_t row = (size_t)blockIdx.x * 4 + wid;
  const float* xr = x + row * W_;
  __shared__ float xs[4][W_];
  for (int q = w; q < W_; q += 64) xs[wid][q] = xr[q];
  __syncthreads();
  float s, c;
  sincosf(TWOPI_256 * (float)w, &s, &c);
  const float stc = c, sts = -s;             // step = cis(-2*pi*w/256)
  float tr = 1.f, ti = 0.f, re = 0.f, im = 0.f;
#pragma unroll 8
  for (int q = 0; q < W_; ++q) {
    float xv = xs[wid][q];
    re = fmaf(xv, tr, re);
    im = fmaf(xv, ti, im);
    float nr = tr * stc - ti * sts;
    float ni = tr * sts + ti * stc;
    tr = nr; ti = ni;
  }
  Xc[row * WC_ + w] = make_float2(re, im);
}

// ---------------------------------------------------------------------------
// Stage B (per chunk): Xf[bi,hr,w] = sum_p Xc[bi,p,w] * cis(-2pi p h(hr)/256)
// h = hr (hr<64) or hr+128. block = chunk-local bi; 512 thr: w=t&63, hg=t>>6
// ---------------------------------------------------------------------------
__global__ __launch_bounds__(512) void kB2(const float2* __restrict__ Xc,
                                           float2* __restrict__ Xf) {
  int bi = blockIdx.x;                        // chunk-local (b*CI + i)
  int w  = threadIdx.x & 63;
  int hg = threadIdx.x >> 6;
  const float2* src = Xc + (size_t)bi * H_ * WC_;
  float2* dst = Xf + (size_t)bi * HR_ * WC_;
  float ar[16], ai[16], tr[16], ti[16], sc[16], ss[16];
#pragma unroll
  for (int k = 0; k < 16; ++k) {
    int hr = hg * 16 + k;
    int h  = (hr < 64) ? hr : hr + 128;
    float s, c;
    sincosf(TWOPI_256 * (float)h, &s, &c);
    sc[k] = c; ss[k] = -s;                    // step = cis(-2*pi*h/256)
    tr[k] = 1.f; ti[k] = 0.f;
    ar[k] = 0.f; ai[k] = 0.f;
  }
#pragma unroll 2
  for (int p = 0; p < H_; ++p) {
    float2 xv = src[(size_t)p * WC_ + w];
#pragma unroll
    for (int k = 0; k < 16; ++k) {
      ar[k] += xv.x * tr[k] - xv.y * ti[k];
      ai[k] += xv.x * ti[k] + xv.y * tr[k];
      float nr = tr[k] * sc[k] - ti[k] * ss[k];
      float ni = tr[k] * ss[k] + ti[k] * sc[k];
      tr[k] = nr; ti[k] = ni;
    }
  }
#pragma unroll
  for (int k = 0; k < 16; ++k) {
    int hr = hg * 16 + k;
    dst[(size_t)hr * WC_ + w] = make_float2(ar[k], ai[k]);
  }
}

// ---------------------------------------------------------------------------
// Stage C: middle (base corners + 15 LoRA experts), unchanged math.
// cell: region = hr>=64, grr = (hr&63)>>4, gc = w>>4, xx = hr&15, yy = w&15
// e = 4*grr+gc-1 (top) / 4*(3-grr)+gc-1 (bottom); e==-1 <=> base cell
// ---------------------------------------------------------------------------
__global__ __launch_bounds__(256) void kC2(
    const float2* __restrict__ Xf, float2* __restrict__ G,
    const float* __restrict__ w1re, const float* __restrict__ w1im,
    const float* __restrict__ w2re, const float* __restrict__ w2im,
    const float* __restrict__ la1re, const float* __restrict__ la1im,
    const float* __restrict__ lb1re, const float* __restrict__ lb1im,
    const float* __restrict__ la2re, const float* __restrict__ la2im,
    const float* __restrict__ lb2re, const float* __restrict__ lb2im,
    const float* __restrict__ gate1, const float* __restrict__ gate2) {
  int b  = blockIdx.x >> 7;
  int hr = blockIdx.x & 127;
  int region = hr >> 6;
  int grr = (hr & 63) >> 4;
  int xx  = hr & 15;
  __shared__ float2 Xs[CI_][WC_];   // 32 KB
  __shared__ float2 Ts[RK_][WC_];   // 2 KB
  int t = threadIdx.x;
  for (int idx = t; idx < CI_ * WC_; idx += 256) {
    int i = idx >> 6, w = idx & 63;
    Xs[i][w] = Xf[(((size_t)b * CI_ + i) * HR_ + hr) * WC_ + w];
  }
  __syncthreads();
  {
    int r = t >> 6, w = t & 63;
    int gc = w >> 4;
    int e = (region == 0) ? (4 * grr + gc - 1) : (4 * (3 - grr) + gc - 1);
    float ar = 0.f, ai = 0.f;
    if (e >= 0) {
      const float* pr = (region == 0 ? la1re : la2re) + ((size_t)e * RK_ + r) * CI_;
      const float* pi = (region == 0 ? la1im : la2im) + ((size_t)e * RK_ + r) * CI_;
#pragma unroll 4
      for (int i = 0; i < CI_; ++i) {
        float2 xv = Xs[i][w];
        float lr = pr[i], li = pi[i];
        ar += lr * xv.x - li * xv.y;
        ai += lr * xv.y + li * xv.x;
      }
    }
    Ts[r][w] = make_float2(ar, ai);
  }
  __syncthreads();
  int w  = t & 63;
  int o0 = (t >> 6) * 16;
  int gc = w >> 4, yy = w & 15;
  int e = (region == 0) ? (4 * grr + gc - 1) : (4 * (3 - grr) + gc - 1);
  if (e < 0) {
    const float* wr = region == 0 ? w1re : w2re;
    const float* wi = region == 0 ? w1im : w2im;
    for (int oo = 0; oo < 16; ++oo) {
      int o = o0 + oo;
      float ar = 0.f, ai = 0.f;
      for (int i = 0; i < CI_; ++i) {
        float2 xv = Xs[i][w];
        size_t widx = (((size_t)i * CO_ + o) * 16 + xx) * 16 + yy;
        float br = wr[widx], bi = wi[widx];
        ar += xv.x * br - xv.y * bi;
        ai += xv.x * bi + xv.y * br;
      }
      G[(((size_t)b * CO_ + o) * HR_ + hr) * WC_ + w] = make_float2(ar, ai);
    }
  } else {
    float gate = (region == 0) ? gate1[e] : gate2[e];
    float g = 0.1f / (1.f + __expf(-gate));   // SCALING * sigmoid(gate)
    const float* br_ = region == 0 ? lb1re : lb2re;
    const float* bi_ = region == 0 ? lb1im : lb2im;
    for (int oo = 0; oo < 16; ++oo) {
      int o = o0 + oo;
      float ar = 0.f, ai = 0.f;
#pragma unroll
      for (int r = 0; r < RK_; ++r) {
        float2 tv = Ts[r][w];
        size_t lidx = ((((size_t)e * CO_ + o) * RK_ + r) * 16 + xx) * 16 + yy;
        float br = br_[lidx], bi = bi_[lidx];
        ar += tv.x * br - tv.y * bi;
        ai += tv.x * bi + tv.y * br;
      }
      G[(((size_t)b * CO_ + o) * HR_ + hr) * WC_ + w] = make_float2(g * ar, g * ai);
    }
  }
}

// ---------------------------------------------------------------------------
// Fused Stage D+E: per (bo, pblk of 64 p's):
//   phase 1: Z[p,w] = sum_hr G[bo,hr,w]*cis(+2pi p h(hr)/256) -> LDS (64x64 c64)
//   phase 2: y[p,q] = (1/65536)*[Re Z0 + 2*sum_{w=1..63} Re(Zw cis(2pi q w/256))]
//   (halfcomplex c2r: Im of bin 0 ignored, bins 64..128 are zero)
//   even/odd-w split: y[q] = (Se+So)/32768, y[q+128] = (Se-So)/32768
// ---------------------------------------------------------------------------
__global__ __launch_bounds__(512) void kDE(const float2* __restrict__ G,
                                           float* __restrict__ y) {
  int bo   = blockIdx.x >> 2;
  int pblk = blockIdx.x & 3;
  int t = threadIdx.x;
  __shared__ float2 Zs[64][64];    // 32 KB
  {
    int w  = t & 63;
    int pg = t >> 6;
    const float2* src = G + (size_t)bo * HR_ * WC_;
    int pbase = pblk * 64 + pg * 8;
    float ar[8], ai[8], tr[8], ti[8], sc[8], ss[8];
#pragma unroll
    for (int k = 0; k < 8; ++k) {
      float s, c;
      sincosf(TWOPI_256 * (float)(pbase + k), &s, &c);
      sc[k] = c; ss[k] = s;                  // step = cis(+2*pi*p/256)
      tr[k] = 1.f; ti[k] = 0.f;
      ar[k] = 0.f; ai[k] = 0.f;
    }
#pragma unroll 2
    for (int h = 0; h < 64; ++h) {           // out_ft rows 0..63
      float2 gv = src[(size_t)h * WC_ + w];
#pragma unroll
      for (int k = 0; k < 8; ++k) {
        ar[k] += gv.x * tr[k] - gv.y * ti[k];
        ai[k] += gv.x * ti[k] + gv.y * tr[k];
        float nr = tr[k] * sc[k] - ti[k] * ss[k];
        float ni = tr[k] * ss[k] + ti[k] * sc[k];
        tr[k] = nr; ti[k] = ni;
      }
    }
#pragma unroll
    for (int k = 0; k < 8; ++k) {            // restart at h=192: cis(2pi p*192/256)
      int pm = (pbase + k) & 3;
      tr[k] = (pm == 0) ? 1.f : (pm == 2) ? -1.f : 0.f;
      ti[k] = (pm == 1) ? -1.f : (pm == 3) ? 1.f : 0.f;
    }
#pragma unroll 2
    for (int h = 64; h < 128; ++h) {         // out_ft rows 192..255
      float2 gv = src[(size_t)h * WC_ + w];
#pragma unroll
      for (int k = 0; k < 8; ++k) {
        ar[k] += gv.x * tr[k] - gv.y * ti[k];
        ai[k] += gv.x * ti[k] + gv.y * tr[k];
        float nr = tr[k] * sc[k] - ti[k] * ss[k];
        float ni = tr[k] * ss[k] + ti[k] * sc[k];
        tr[k] = nr; ti[k] = ni;
      }
    }
#pragma unroll
    for (int k = 0; k < 8; ++k)
      Zs[pg * 8 + k][w] = make_float2(ar[k], ai[k]);
  }
  __syncthreads();
  {
    int q   = t & 127;
    int pg2 = t >> 7;                        // 4 groups x 16 local p's
    float s, c;
    sincosf(TWOPI_256 * (float)q, &s, &c);
    const float stc = c, sts = s;            // step = cis(+2*pi*q/256)
    float se[16], so[16];
#pragma unroll
    for (int j = 0; j < 16; ++j) {
      se[j] = 0.5f * Zs[pg2 * 16 + j][0].x;  // w=0 term coeff 1 (= 2*(1/2))
      so[j] = 0.f;
    }
    float tr = stc, ti = sts;                // state at w=1
#pragma unroll 2
    for (int w = 1; w < 64; ++w) {
#pragma unroll
      for (int j = 0; j < 16; ++j) {
        float2 a = Zs[pg2 * 16 + j][w];
        float term = a.x * tr - a.y * ti;    // Re(Z[w]*cis(2pi q w/256))
        if (w & 1) so[j] += term; else se[j] += term;
      }
      float nr = tr * stc - ti * sts;
      float ni = tr * sts + ti * stc;
      tr = nr; ti = ni;
    }
    const float scale = 1.f / 32768.f;       // 2/(256*256)
#pragma unroll
    for (int j = 0; j < 16; ++j) {
      int p = pblk * 64 + pg2 * 16 + j;
      float* dst = y + ((size_t)bo * H_ + p) * W_;
      dst[q]       = (se[j] + so[j]) * scale;
      dst[q + 128] = (se[j] - so[j]) * scale;
    }
  }
}

// ---------------------------------------------------------------------------
// sploss = mean(sigmoid(gate1)) + mean(sigmoid(gate2))  (fp32 output)
// ---------------------------------------------------------------------------
__global__ void kS2(const float* __restrict__ gate1, const float* __restrict__ gate2,
                    float* __restrict__ out) {
  if (threadIdx.x == 0) {
    float s = 0.f;
    for (int e = 0; e < NE_; ++e)
      s += 1.f / (1.f + expf(-gate1[e])) + 1.f / (1.f + expf(-gate2[e]));
    out[0] = s / (float)NE_;
  }
}

extern "C" void kernel_launch(void* const* d_in, const int* in_sizes, int n_in,
                              void* d_out, int out_size, void* d_ws, size_t ws_size,
                              hipStream_t stream) {
  const float* x     = (const float*)d_in[0];
  const float* w1re  = (const float*)d_in[1];
  const float* w1im  = (const float*)d_in[2];
  const float* w2re  = (const float*)d_in[3];
  const float* w2im  = (const float*)d_in[4];
  const float* la1re = (const float*)d_in[5];
  const float* la1im = (const float*)d_in[6];
  const float* lb1re = (const float*)d_in[7];
  const float* lb1im = (const float*)d_in[8];
  const float* la2re = (const float*)d_in[9];
  const float* la2im = (const float*)d_in[10];
  const float* lb2re = (const float*)d_in[11];
  const float* lb2im = (const float*)d_in[12];
  const float* gate1 = (const float*)d_in[13];
  const float* gate2 = (const float*)d_in[14];

  // Workspace (64 MiB peak):
  //   Xf: [B,CI,128,64] float2 = 32 MiB @ 0          (live: kB2 -> kC2)
  //   Xc: [NB_,CI,256,64] float2 = 32 MiB @ 32 MiB   (live per A/B chunk)
  //   G : [B,CO,128,64] float2 = 32 MiB @ 32 MiB     (overwrites Xc after A/B)
  char* ws = (char*)d_ws;
  float2* Xf = (float2*)ws;
  float2* Xc = (float2*)(ws + (size_t)32 * 1024 * 1024);
  float2* G  = (float2*)(ws + (size_t)32 * 1024 * 1024);
  float* y = (float*)d_out;

  for (int cchunk = 0; cchunk < B_ / NB_; ++cchunk) {
    const float* xsrc = x + (size_t)cchunk * NB_ * CI_ * H_ * W_;
    float2* xfdst = Xf + (size_t)cchunk * NB_ * CI_ * HR_ * WC_;
    kA2<<<NB_ * CI_ * H_ / 4, 256, 0, stream>>>(xsrc, Xc);
    kB2<<<NB_ * CI_, 512, 0, stream>>>(Xc, xfdst);
  }
  kC2<<<B_ * HR_, 256, 0, stream>>>(Xf, G, w1re, w1im, w2re, w2im,
                                    la1re, la1im, lb1re, lb1im,
                                    la2re, la2im, lb2re, lb2im, gate1, gate2);
  kDE<<<B_ * CO_ * 4, 512, 0, stream>>>(G, y);
  kS2<<<1, 64, 0, stream>>>(gate1, gate2, y + (size_t)B_ * CO_ * H_ * W_);
}

// Round 3
// 531.896 us; speedup vs baseline: 2.4821x; 2.4821x over previous
//
#include <hip/hip_runtime.h>
#include <math.h>

// Problem constants
#define B_   8
#define CI_  64
#define CO_  64
#define H_   256
#define W_   256
#define NE_  15
#define RK_  4

typedef __attribute__((ext_vector_type(8))) short short8;   // MFMA A/B frag (8 bf16)
typedef __attribute__((ext_vector_type(4))) float f32x4;    // MFMA C/D frag

__device__ __forceinline__ unsigned bf16u(float f) {
  return (__float_as_uint(f) + 0x8000u) >> 16;              // round-to-nearest-ish
}
__device__ __forceinline__ unsigned pk2(float lo, float hi) {
  return ((__float_as_uint(lo) + 0x8000u) >> 16) |
         ((__float_as_uint(hi) + 0x8000u) & 0xFFFF0000u);
}
__device__ __forceinline__ float ubf(unsigned short u) {
  return __uint_as_float(((unsigned)u) << 16);
}

// ---------------------------------------------------------------------------
// Table generation (bf16). All angles reduced exactly mod 256.
//  TAt [n=2w+pl][q]     : pl=0 cos(2pi qw/256), pl=1 -sin  (rfft over W)
//  TB  [m=hr-plane][k=2p+pl]: Re rows [c | s], Im rows [-s | c]  (c,s of 2pi p h/256)
//  TD  [m=p-plane][k=2hr+pl]: Re rows [c | -s], Im rows [s | c]  (inverse over H)
//  TEt [q][k=2w+pl]     : pl=0 (w==0?1:2c)/65536, pl=1 (w==0?0:-2s)/65536
// ---------------------------------------------------------------------------
__global__ __launch_bounds__(256) void kTab(unsigned short* __restrict__ TAt,
                                            unsigned short* __restrict__ TB,
                                            unsigned short* __restrict__ TD,
                                            unsigned short* __restrict__ TEt) {
  int idx = blockIdx.x * 256 + threadIdx.x;
  const float C = 6.28318530717958647692f / 256.f;
  if (idx < 32768) {                       // TAt [128][256]
    int n = idx >> 8, q = idx & 255;
    int w = n >> 1, pl = n & 1;
    int mm = (q * w) & 255;
    float s, c; sincosf(C * (float)mm, &s, &c);
    TAt[idx] = (unsigned short)bf16u(pl ? -s : c);
    return;
  }
  idx -= 32768;
  if (idx < 131072) {                      // TB [256][512]
    int mrow = idx >> 9, k = idx & 511;
    int p = k >> 1, tt = k & 1;
    int hr = mrow & 127, imr = mrow >> 7;
    int h = (hr < 64) ? hr : hr + 128;
    int mm = (p * h) & 255;
    float s, c; sincosf(C * (float)mm, &s, &c);
    float v = (imr == 0) ? (tt == 0 ? c : s) : (tt == 0 ? -s : c);
    TB[idx] = (unsigned short)bf16u(v);
    return;
  }
  idx -= 131072;
  if (idx < 131072) {                      // TD [512][256]
    int mrow = idx >> 8, k = idx & 255;
    int hr = k >> 1, tt = k & 1;
    int p = mrow & 255, imr = mrow >> 8;
    int h = (hr < 64) ? hr : hr + 128;
    int mm = (p * h) & 255;
    float s, c; sincosf(C * (float)mm, &s, &c);
    float v = (imr == 0) ? (tt == 0 ? c : -s) : (tt == 0 ? s : c);
    TD[idx] = (unsigned short)bf16u(v);
    return;
  }
  idx -= 131072;
  if (idx < 32768) {                       // TEt [256][128]
    int q = idx >> 7, k = idx & 127;
    int w = k >> 1, pl = k & 1;
    int mm = (q * w) & 255;
    float s, c; sincosf(C * (float)mm, &s, &c);
    float v = (pl == 0) ? ((w == 0 ? 1.f : 2.f * c) / 65536.f)
                        : ((w == 0 ? 0.f : -2.f * s) / 65536.f);
    TEt[idx] = (unsigned short)bf16u(v);
  }
}

// ---------------------------------------------------------------------------
// Stage A: C[m,n] = x[m, q=256] * TAt^T   (M=131072, K=256, N=128)
// m = (b,i,p); n = 2w+pl. Epilogue transposes to XcT[b,i][w][k=2p+pl].
// 256 thr = 4 waves, 128x128 tile, BK=32, 8 K-steps.
// ---------------------------------------------------------------------------
__global__ __launch_bounds__(256) void kGA(const float* __restrict__ x,
                                           const unsigned short* __restrict__ TAt,
                                           unsigned short* __restrict__ XcT) {
  __shared__ unsigned short As[128 * 32];   // 8 KB  (data, bf16)
  __shared__ unsigned short Bs[128 * 32];   // 8 KB  (table rows [n][k])
  __shared__ unsigned short Tt[64 * 264];   // 33 KB (epilogue transpose, pad 264)
  int t = threadIdx.x;
  int lane = t & 63, wid = t >> 6;
  int row0 = blockIdx.x * 128;
  int mb = (wid >> 1) * 64, nb = (wid & 1) * 64;
  int lrow = lane & 15, lk = (lane >> 4) * 8;
  f32x4 acc[4][4];
#pragma unroll
  for (int a = 0; a < 4; ++a)
#pragma unroll
    for (int b = 0; b < 4; ++b) acc[a][b] = (f32x4){0.f, 0.f, 0.f, 0.f};

  for (int kk = 0; kk < 8; ++kk) {
    int k0 = kk * 32;
    __syncthreads();
    {   // stage x tile fp32 -> bf16 : rows 128 x 32k
      int r = t >> 1, hf = t & 1;
      const float* xp = x + (size_t)(row0 + r) * 256 + k0 + hf * 16;
      float4 v0 = *(const float4*)(xp);
      float4 v1 = *(const float4*)(xp + 4);
      float4 v2 = *(const float4*)(xp + 8);
      float4 v3 = *(const float4*)(xp + 12);
      uint4 o0, o1;
      o0.x = pk2(v0.x, v0.y); o0.y = pk2(v0.z, v0.w);
      o0.z = pk2(v1.x, v1.y); o0.w = pk2(v1.z, v1.w);
      o1.x = pk2(v2.x, v2.y); o1.y = pk2(v2.z, v2.w);
      o1.z = pk2(v3.x, v3.y); o1.w = pk2(v3.z, v3.w);
      uint4* dst = (uint4*)&As[r * 32 + hf * 16];
      dst[0] = o0; dst[1] = o1;
    }
#pragma unroll
    for (int j = 0; j < 2; ++j) {   // stage TAt tile: 128 rows x 32k
      int c = j * 256 + t;
      int n = c >> 2, seg = c & 3;
      *(uint4*)&Bs[n * 32 + seg * 8] = *(const uint4*)&TAt[n * 256 + k0 + seg * 8];
    }
    __syncthreads();
    short8 af[4], bf[4];
#pragma unroll
    for (int a = 0; a < 4; ++a)
      af[a] = *(const short8*)&As[(mb + a * 16 + lrow) * 32 + lk];
#pragma unroll
    for (int b = 0; b < 4; ++b)
      bf[b] = *(const short8*)&Bs[(nb + b * 16 + lrow) * 32 + lk];
#pragma unroll
    for (int a = 0; a < 4; ++a)
#pragma unroll
      for (int b = 0; b < 4; ++b)
        acc[a][b] = __builtin_amdgcn_mfma_f32_16x16x32_bf16(af[a], bf[b], acc[a][b], 0, 0, 0);
  }
  // epilogue: C[m][n] -> Tt[w=n>>1][2m + (n&1)], then coalesced store
#pragma unroll
  for (int a = 0; a < 4; ++a)
#pragma unroll
    for (int b = 0; b < 4; ++b)
#pragma unroll
      for (int r = 0; r < 4; ++r) {
        int m = mb + a * 16 + (lane >> 4) * 4 + r;
        int n = nb + b * 16 + lrow;
        Tt[(n >> 1) * 264 + 2 * m + (n & 1)] = (unsigned short)bf16u(acc[a][b][r]);
      }
  __syncthreads();
  {
    int bi = row0 >> 8;
    int p0 = row0 & 255;              // 0 or 128
    int w = t >> 2, seg = t & 3;
    unsigned short* dst = XcT + (size_t)bi * 32768 + w * 512 + p0 * 2 + seg * 64;
    const unsigned short* src = &Tt[w * 264 + seg * 64];
#pragma unroll
    for (int j = 0; j < 8; ++j)
      *(uint4*)(dst + j * 8) = *(const uint4*)(src + j * 8);
  }
}

// ---------------------------------------------------------------------------
// Stage B: per (b,i): Xf[m=hr-plane 256][w 64] = TB[256x512] * XcT[b,i][512x64]
// A = TB rows [m][k]; B = XcT rows [w][k] (pre-transposed). BK=32, 16 steps.
// ---------------------------------------------------------------------------
__global__ __launch_bounds__(256) void kGB(const unsigned short* __restrict__ XcT,
                                           const unsigned short* __restrict__ TB,
                                           unsigned short* __restrict__ Xf) {
  __shared__ unsigned short As[256 * 32];   // 16 KB
  __shared__ unsigned short Bs[64 * 32];    // 4 KB
  int t = threadIdx.x, lane = t & 63, wid = t >> 6;
  int bi = blockIdx.x;
  const unsigned short* Xrow = XcT + (size_t)bi * 32768;
  int mb = wid * 64;
  int lrow = lane & 15, lk = (lane >> 4) * 8;
  f32x4 acc[4][4];
#pragma unroll
  for (int a = 0; a < 4; ++a)
#pragma unroll
    for (int b = 0; b < 4; ++b) acc[a][b] = (f32x4){0.f, 0.f, 0.f, 0.f};

  for (int kk = 0; kk < 16; ++kk) {
    int k0 = kk * 32;
    __syncthreads();
#pragma unroll
    for (int j = 0; j < 4; ++j) {            // TB tile 256x32
      int c = j * 256 + t;
      int m = c >> 2, seg = c & 3;
      *(uint4*)&As[m * 32 + seg * 8] = *(const uint4*)&TB[m * 512 + k0 + seg * 8];
    }
    {                                        // data tile 64x32
      int n = t >> 2, seg = t & 3;
      *(uint4*)&Bs[n * 32 + seg * 8] = *(const uint4*)&Xrow[n * 512 + k0 + seg * 8];
    }
    __syncthreads();
    short8 af[4], bf[4];
#pragma unroll
    for (int a = 0; a < 4; ++a)
      af[a] = *(const short8*)&As[(mb + a * 16 + lrow) * 32 + lk];
#pragma unroll
    for (int b = 0; b < 4; ++b)
      bf[b] = *(const short8*)&Bs[(b * 16 + lrow) * 32 + lk];
#pragma unroll
    for (int a = 0; a < 4; ++a)
#pragma unroll
      for (int b = 0; b < 4; ++b)
        acc[a][b] = __builtin_amdgcn_mfma_f32_16x16x32_bf16(af[a], bf[b], acc[a][b], 0, 0, 0);
  }
  unsigned short* dst = Xf + (size_t)bi * 16384;
#pragma unroll
  for (int a = 0; a < 4; ++a)
#pragma unroll
    for (int b = 0; b < 4; ++b)
#pragma unroll
      for (int r = 0; r < 4; ++r) {
        int m = mb + a * 16 + (lane >> 4) * 4 + r;
        int n = b * 16 + lrow;
        dst[m * 64 + n] = (unsigned short)bf16u(acc[a][b][r]);
      }
}

// ---------------------------------------------------------------------------
// Stage C: MoE middle (fp32 VALU). Reads Xf bf16 [b,i][m][w], writes
// Gt bf16 [b,o][w][k=2hr+pl].
// ---------------------------------------------------------------------------
__global__ __launch_bounds__(256) void kC3(
    const unsigned short* __restrict__ Xf, unsigned short* __restrict__ Gt,
    const float* __restrict__ w1re, const float* __restrict__ w1im,
    const float* __restrict__ w2re, const float* __restrict__ w2im,
    const float* __restrict__ la1re, const float* __restrict__ la1im,
    const float* __restrict__ lb1re, const float* __restrict__ lb1im,
    const float* __restrict__ la2re, const float* __restrict__ la2im,
    const float* __restrict__ lb2re, const float* __restrict__ lb2im,
    const float* __restrict__ gate1, const float* __restrict__ gate2) {
  int b  = blockIdx.x >> 7;
  int hr = blockIdx.x & 127;
  int region = hr >> 6;
  int grr = (hr & 63) >> 4;
  int xx  = hr & 15;
  __shared__ float2 Xs[CI_][64];    // 32 KB
  __shared__ float2 Ts[RK_][64];    // 2 KB
  int t = threadIdx.x;
  for (int idx = t; idx < CI_ * 64; idx += 256) {
    int i = idx >> 6, w = idx & 63;
    const unsigned short* base = Xf + (size_t)(b * CI_ + i) * 16384;
    Xs[i][w] = make_float2(ubf(base[hr * 64 + w]), ubf(base[(128 + hr) * 64 + w]));
  }
  __syncthreads();
  {
    int r = t >> 6, w = t & 63;
    int gc = w >> 4;
    int e = (region == 0) ? (4 * grr + gc - 1) : (4 * (3 - grr) + gc - 1);
    float ar = 0.f, ai = 0.f;
    if (e >= 0) {
      const float* pr = (region == 0 ? la1re : la2re) + ((size_t)e * RK_ + r) * CI_;
      const float* pi = (region == 0 ? la1im : la2im) + ((size_t)e * RK_ + r) * CI_;
#pragma unroll 4
      for (int i = 0; i < CI_; ++i) {
        float2 xv = Xs[i][w];
        float lr = pr[i], li = pi[i];
        ar += lr * xv.x - li * xv.y;
        ai += lr * xv.y + li * xv.x;
      }
    }
    Ts[r][w] = make_float2(ar, ai);
  }
  __syncthreads();
  int w  = t & 63;
  int o0 = (t >> 6) * 16;
  int gc = w >> 4, yy = w & 15;
  int e = (region == 0) ? (4 * grr + gc - 1) : (4 * (3 - grr) + gc - 1);
  if (e < 0) {
    const float* wr = region == 0 ? w1re : w2re;
    const float* wi = region == 0 ? w1im : w2im;
    for (int oo = 0; oo < 16; ++oo) {
      int o = o0 + oo;
      float ar = 0.f, ai = 0.f;
      for (int i = 0; i < CI_; ++i) {
        float2 xv = Xs[i][w];
        size_t widx = (((size_t)i * CO_ + o) * 16 + xx) * 16 + yy;
        float br = wr[widx], bi = wi[widx];
        ar += xv.x * br - xv.y * bi;
        ai += xv.x * bi + xv.y * br;
      }
      *(unsigned*)(Gt + ((size_t)(b * CO_ + o) * 64 + w) * 256 + 2 * hr) = pk2(ar, ai);
    }
  } else {
    float gate = (region == 0) ? gate1[e] : gate2[e];
    float g = 0.1f / (1.f + __expf(-gate));
    const float* br_ = region == 0 ? lb1re : lb2re;
    const float* bi_ = region == 0 ? lb1im : lb2im;
    for (int oo = 0; oo < 16; ++oo) {
      int o = o0 + oo;
      float ar = 0.f, ai = 0.f;
#pragma unroll
      for (int r = 0; r < RK_; ++r) {
        float2 tv = Ts[r][w];
        size_t lidx = ((((size_t)e * CO_ + o) * RK_ + r) * 16 + xx) * 16 + yy;
        float br = br_[lidx], bi = bi_[lidx];
        ar += tv.x * br - tv.y * bi;
        ai += tv.x * bi + tv.y * br;
      }
      *(unsigned*)(Gt + ((size_t)(b * CO_ + o) * 64 + w) * 256 + 2 * hr) = pk2(g * ar, g * ai);
    }
  }
}

// ---------------------------------------------------------------------------
// Stage D: per (b,o): Z[m=p-plane 512][w 64] = TD[512x256] * Gt[b,o][256x64]
// Epilogue writes Zt[b,o][p][k=2w+pl]. 512 thr = 8 waves. BK=32, 8 steps.
// ---------------------------------------------------------------------------
__global__ __launch_bounds__(512) void kGD(const unsigned short* __restrict__ Gt,
                                           const unsigned short* __restrict__ TD,
                                           unsigned short* __restrict__ Zt) {
  __shared__ unsigned short As[512 * 32];   // 32 KB
  __shared__ unsigned short Bs[64 * 32];    // 4 KB
  int t = threadIdx.x, lane = t & 63, wid = t >> 6;
  int bo = blockIdx.x;
  const unsigned short* Grow = Gt + (size_t)bo * 16384;
  int mb = wid * 64;
  int lrow = lane & 15, lk = (lane >> 4) * 8;
  f32x4 acc[4][4];
#pragma unroll
  for (int a = 0; a < 4; ++a)
#pragma unroll
    for (int b = 0; b < 4; ++b) acc[a][b] = (f32x4){0.f, 0.f, 0.f, 0.f};

  for (int kk = 0; kk < 8; ++kk) {
    int k0 = kk * 32;
    __syncthreads();
#pragma unroll
    for (int j = 0; j < 4; ++j) {            // TD tile 512x32
      int c = j * 512 + t;
      int m = c >> 2, seg = c & 3;
      *(uint4*)&As[m * 32 + seg * 8] = *(const uint4*)&TD[m * 256 + k0 + seg * 8];
    }
    if (t < 256) {                           // data tile 64x32
      int n = t >> 2, seg = t & 3;
      *(uint4*)&Bs[n * 32 + seg * 8] = *(const uint4*)&Grow[n * 256 + k0 + seg * 8];
    }
    __syncthreads();
    short8 af[4], bf[4];
#pragma unroll
    for (int a = 0; a < 4; ++a)
      af[a] = *(const short8*)&As[(mb + a * 16 + lrow) * 32 + lk];
#pragma unroll
    for (int b = 0; b < 4; ++b)
      bf[b] = *(const short8*)&Bs[(b * 16 + lrow) * 32 + lk];
#pragma unroll
    for (int a = 0; a < 4; ++a)
#pragma unroll
      for (int b = 0; b < 4; ++b)
        acc[a][b] = __builtin_amdgcn_mfma_f32_16x16x32_bf16(af[a], bf[b], acc[a][b], 0, 0, 0);
  }
  unsigned short* dst = Zt + (size_t)bo * 32768;
#pragma unroll
  for (int a = 0; a < 4; ++a)
#pragma unroll
    for (int b = 0; b < 4; ++b)
#pragma unroll
      for (int r = 0; r < 4; ++r) {
        int m = mb + a * 16 + (lane >> 4) * 4 + r;
        int p = m & 255, pl = m >> 8;
        int n = b * 16 + lrow;
        dst[p * 128 + 2 * n + pl] = (unsigned short)bf16u(acc[a][b][r]);
      }
}

// ---------------------------------------------------------------------------
// Stage E: per (b,o,qhalf): y[p 256][q 128] = Zt[b,o][256x128] * TEt^T
// A = Zt rows [p][k]; B = TEt rows [q][k]. BK=32, 4 steps. fp32 stores.
// ---------------------------------------------------------------------------
__global__ __launch_bounds__(512) void kGE(const unsigned short* __restrict__ Zt,
                                           const unsigned short* __restrict__ TEt,
                                           float* __restrict__ y) {
  __shared__ unsigned short As[256 * 32];   // 16 KB
  __shared__ unsigned short Bs[128 * 32];   // 8 KB
  int t = threadIdx.x, lane = t & 63, wid = t >> 6;
  int bo = blockIdx.x >> 1, qh = blockIdx.x & 1;
  const unsigned short* Zrow = Zt + (size_t)bo * 32768;
  int mb = (wid >> 1) * 64, nb = (wid & 1) * 64;
  int lrow = lane & 15, lk = (lane >> 4) * 8;
  f32x4 acc[4][4];
#pragma unroll
  for (int a = 0; a < 4; ++a)
#pragma unroll
    for (int b = 0; b < 4; ++b) acc[a][b] = (f32x4){0.f, 0.f, 0.f, 0.f};

  for (int kk = 0; kk < 4; ++kk) {
    int k0 = kk * 32;
    __syncthreads();
#pragma unroll
    for (int j = 0; j < 2; ++j) {            // Zt tile 256x32
      int c = j * 512 + t;
      int m = c >> 2, seg = c & 3;
      *(uint4*)&As[m * 32 + seg * 8] = *(const uint4*)&Zrow[m * 128 + k0 + seg * 8];
    }
    {                                        // TEt tile 128x32
      int n = t >> 2, seg = t & 3;
      *(uint4*)&Bs[n * 32 + seg * 8] =
          *(const uint4*)&TEt[(qh * 128 + n) * 128 + k0 + seg * 8];
    }
    __syncthreads();
    short8 af[4], bf[4];
#pragma unroll
    for (int a = 0; a < 4; ++a)
      af[a] = *(const short8*)&As[(mb + a * 16 + lrow) * 32 + lk];
#pragma unroll
    for (int b = 0; b < 4; ++b)
      bf[b] = *(const short8*)&Bs[(nb + b * 16 + lrow) * 32 + lk];
#pragma unroll
    for (int a = 0; a < 4; ++a)
#pragma unroll
      for (int b = 0; b < 4; ++b)
        acc[a][b] = __builtin_amdgcn_mfma_f32_16x16x32_bf16(af[a], bf[b], acc[a][b], 0, 0, 0);
  }
  float* dst = y + (size_t)bo * 65536 + qh * 128;
#pragma unroll
  for (int a = 0; a < 4; ++a)
#pragma unroll
    for (int b = 0; b < 4; ++b)
#pragma unroll
      for (int r = 0; r < 4; ++r) {
        int p = mb + a * 16 + (lane >> 4) * 4 + r;
        int q = nb + b * 16 + lrow;
        dst[(size_t)p * 256 + q] = acc[a][b][r];
      }
}

// ---------------------------------------------------------------------------
// sploss = mean(sigmoid(gate1)) + mean(sigmoid(gate2))  (fp32)
// ---------------------------------------------------------------------------
__global__ void kS2(const float* __restrict__ gate1, const float* __restrict__ gate2,
                    float* __restrict__ out) {
  if (threadIdx.x == 0) {
    float s = 0.f;
    for (int e = 0; e < NE_; ++e)
      s += 1.f / (1.f + expf(-gate1[e])) + 1.f / (1.f + expf(-gate2[e]));
    out[0] = s / (float)NE_;
  }
}

extern "C" void kernel_launch(void* const* d_in, const int* in_sizes, int n_in,
                              void* d_out, int out_size, void* d_ws, size_t ws_size,
                              hipStream_t stream) {
  const float* x     = (const float*)d_in[0];
  const float* w1re  = (const float*)d_in[1];
  const float* w1im  = (const float*)d_in[2];
  const float* w2re  = (const float*)d_in[3];
  const float* w2im  = (const float*)d_in[4];
  const float* la1re = (const float*)d_in[5];
  const float* la1im = (const float*)d_in[6];
  const float* lb1re = (const float*)d_in[7];
  const float* lb1im = (const float*)d_in[8];
  const float* la2re = (const float*)d_in[9];
  const float* la2im = (const float*)d_in[10];
  const float* lb2re = (const float*)d_in[11];
  const float* lb2im = (const float*)d_in[12];
  const float* gate1 = (const float*)d_in[13];
  const float* gate2 = (const float*)d_in[14];

  // Workspace layout (bf16 halfwords), ~96.6 MiB peak (round 0/1 touched 128 MiB
  // without fault):
  //   XcT @  0 MiB : [b,i][w 64][k=2p+pl 512]   32 MiB
  //   Xf  @ 32 MiB : [b,i][m=hr-plane 256][w 64] 16 MiB
  //   Gt  @ 48 MiB : [b,o][w 64][k=2hr+pl 256]  16 MiB
  //   Zt  @ 64 MiB : [b,o][p 256][k=2w+pl 128]  32 MiB
  //   tables @ 96 MiB : TAt 64K, TB 256K, TD 256K, TEt 64K
  char* ws = (char*)d_ws;
  unsigned short* XcT = (unsigned short*)ws;
  unsigned short* Xf  = (unsigned short*)(ws + ((size_t)32 << 20));
  unsigned short* Gt  = (unsigned short*)(ws + ((size_t)48 << 20));
  unsigned short* Zt  = (unsigned short*)(ws + ((size_t)64 << 20));
  unsigned short* TAt = (unsigned short*)(ws + ((size_t)96 << 20));
  unsigned short* TB  = TAt + 32768;
  unsigned short* TD  = TB + 131072;
  unsigned short* TEt = TD + 131072;
  float* y = (float*)d_out;

  kTab<<<1280, 256, 0, stream>>>(TAt, TB, TD, TEt);
  kGA<<<1024, 256, 0, stream>>>(x, TAt, XcT);
  kGB<<<512, 256, 0, stream>>>(XcT, TB, Xf);
  kC3<<<1024, 256, 0, stream>>>(Xf, Gt, w1re, w1im, w2re, w2im,
                                la1re, la1im, lb1re, lb1im,
                                la2re, la2im, lb2re, lb2im, gate1, gate2);
  kGD<<<512, 512, 0, stream>>>(Gt, TD, Zt);
  kGE<<<1024, 512, 0, stream>>>(Zt, TEt, y);
  kS2<<<1, 64, 0, stream>>>(gate1, gate2, y + (size_t)B_ * CO_ * H_ * W_);
}